// Round 1
// baseline (178.167 us; speedup 1.0000x reference)
//
#include <hip/hip_runtime.h>

typedef _Float16 f16;
typedef _Float16 f16x4 __attribute__((ext_vector_type(4)));
typedef _Float16 f16x8 __attribute__((ext_vector_type(8)));
typedef float f32x4 __attribute__((ext_vector_type(4)));

// A[px][k]: 16 px rows x 2048 f16 (4096 B per row). 16-B chunks XOR-swizzled
// by px (4 bits): byte = px*4096 + ((k>>3)^(px&15))*16 + (k&7)*2.
static __device__ inline char* a_addr(char* Abase, int px, int k) {
    return Abase + px * 4096 + ((((k >> 3) ^ (px & 15)) << 4) | ((k & 7) << 1));
}

// ---------------------------------------------------------------------------
// k_setup: one launch, no internal deps.
// blocks 0..63:   (b,e): full query path redundantly
// blocks 64..319: M_e = Wv_e @ w_out_e, rw-folded -> mtp[kchunk][o][8] f16
// ---------------------------------------------------------------------------
__launch_bounds__(256)
__global__ void k_setup(const int* __restrict__ q, const float* __restrict__ emb,
                        const float* __restrict__ w1, const float* __restrict__ b1,
                        const float* __restrict__ w2, const float* __restrict__ b2,
                        const float* __restrict__ w_kv, const float* __restrict__ w_out,
                        const float* __restrict__ rms_w,
                        f16* __restrict__ qkw, f16* __restrict__ mtp) {
    int blk = blockIdx.x;
    int t = threadIdx.x;
    __shared__ float qe[256];
    __shared__ float x1L[512];
    __shared__ float ps[4][64];
    __shared__ float qhL[64];
    __shared__ float wv[64][8];

    if (blk < 64) {
        // ---- query-path role: (b, e) ----
        int b = blk >> 3, e = blk & 7;
        qe[t] = emb[(size_t)q[b] * 256 + t];
        __syncthreads();
        float a0 = b1[t], a1 = b1[t + 256];
#pragma unroll 4
        for (int c = 0; c < 256; ++c) {
            float qv = qe[c];
            a0 += qv * w1[c * 512 + t];
            a1 += qv * w1[c * 512 + t + 256];
        }
        x1L[t]       = a0 / (1.f + __expf(-a0));
        x1L[t + 256] = a1 / (1.f + __expf(-a1));
        __syncthreads();
        int d = t & 63, ks = t >> 6;
        float acc = 0.f;
#pragma unroll 4
        for (int k = ks * 128; k < ks * 128 + 128; ++k)
            acc += x1L[k] * w2[k * 512 + e * 64 + d];
        ps[ks][d] = acc;
        __syncthreads();
        if (t < 64)
            qhL[t] = b2[e * 64 + t] + ps[0][t] + ps[1][t] + ps[2][t] + ps[3][t];
        __syncthreads();
        const float* row = w_kv + (size_t)t * 1024 + e * 128;   // K-half of head e
        float a2 = 0.f;
#pragma unroll
        for (int dd = 0; dd < 64; dd += 4) {
            float4 wv4 = *(const float4*)(row + dd);
            a2 += qhL[dd] * wv4.x + qhL[dd + 1] * wv4.y + qhL[dd + 2] * wv4.z + qhL[dd + 3] * wv4.w;
        }
        qkw[(b * 8 + e) * 256 + t] = (f16)(a2 * rms_w[t]);
    } else {
        // ---- M role: (e, 8-c tile) ----
        int mb = blk - 64;
        int e = mb >> 5, c0 = (mb & 31) * 8;
        {
            int d = t & 63, cc = t >> 6;
            wv[d][cc]     = w_kv[(size_t)(c0 + cc) * 1024 + e * 128 + 64 + d];
            wv[d][cc + 4] = w_kv[(size_t)(c0 + cc + 4) * 1024 + e * 128 + 64 + d];
        }
        __syncthreads();
        int o = t;
        float acc[8];
#pragma unroll
        for (int c = 0; c < 8; ++c) acc[c] = 0.f;
#pragma unroll 4
        for (int d = 0; d < 64; ++d) {
            float wo = w_out[(size_t)(e * 64 + d) * 256 + o];
            float4 wa = *(const float4*)&wv[d][0];
            float4 wb = *(const float4*)&wv[d][4];
            acc[0] += wa.x * wo; acc[1] += wa.y * wo; acc[2] += wa.z * wo; acc[3] += wa.w * wo;
            acc[4] += wb.x * wo; acc[5] += wb.y * wo; acc[6] += wb.z * wo; acc[7] += wb.w * wo;
        }
        f16x8 ov;
#pragma unroll
        for (int c = 0; c < 8; ++c) ov[c] = (f16)(acc[c] * rms_w[c0 + c]);
        *(f16x8*)(mtp + ((size_t)((e * 256 + c0) >> 3) * 256 + o) * 8) = ov;
    }
}

// ---------------------------------------------------------------------------
// k_attn v2: 1024 threads, 16 pixels/block, grid 512 (tile*8 + b).
// 2 blocks/CU (LDS 71 KiB, VGPR target <=64 via __launch_bounds__(1024,8)) so
// one block's HBM load phase overlaps the other block's L2-bound GEMM phase.
// phases: [load + sumsq] -> [dots MFMA (w<8) || rinv (w 8-9)] ->
//         [fused softmax+blend in place] -> [GEMM: wave w -> o 16-slice] -> store.
// ---------------------------------------------------------------------------
__launch_bounds__(1024, 8)
__global__ void k_attn(const float* __restrict__ cin, const f16* __restrict__ qkw,
                       const f16* __restrict__ mtp, const float* __restrict__ b_out,
                       float* __restrict__ out) {
    int blk = blockIdx.x;
    int b = blk & 7;                      // XCD = blk%8 = b -> c[b] stays XCD-local
    int hw0 = (blk >> 3) * 16;
    int t = threadIdx.x;
    int lane = t & 63, w = t >> 6;        // w 0..15
    int m16 = lane & 15, quad = lane >> 4;

    __shared__ char A[16 * 4096];         // 65536 B, swizzled f16 [16px][2048k]
    __shared__ float dotsP[8][8][16];     //  4096 B [n][e][px]
    __shared__ float wred[16][16];        //  1024 B [w][px]
    __shared__ float rinvL[16][9];        //   576 B [px][n], pad 9 -> conflict-free

    // ---- load raw c -> A (f16, swizzled) + partial sumsq ----
    // thread = (px = m16, cb = w*4+quad): rows k = cb*32 .. cb*32+31 at col hw0+px.
    // All 32 values of a thread share one (px, n): n = cb>>3.
    {
        int px = m16;
        int cb = (w << 2) | quad;         // 0..63
        const float* src = cin + ((size_t)b * 2048 + (size_t)cb * 32) * 1024 + hw0 + px;
        float ss = 0.f;
#pragma unroll
        for (int jb = 0; jb < 4; jb += 2) {   // 2 iters, 16 loads in flight each
            float v0[8], v1[8];
#pragma unroll
            for (int j = 0; j < 8; ++j) v0[j] = src[(size_t)(jb * 8 + j) << 10];
#pragma unroll
            for (int j = 0; j < 8; ++j) v1[j] = src[(size_t)(jb * 8 + 8 + j) << 10];
            f16x8 h0, h1;
#pragma unroll
            for (int j = 0; j < 8; ++j) { ss += v0[j] * v0[j]; h0[j] = (f16)v0[j]; }
#pragma unroll
            for (int j = 0; j < 8; ++j) { ss += v1[j] * v1[j]; h1[j] = (f16)v1[j]; }
            *(f16x8*)a_addr(A, px, cb * 32 + jb * 8)     = h0;
            *(f16x8*)a_addr(A, px, cb * 32 + jb * 8 + 8) = h1;
        }
        // reduce over the 4 quad groups (same px, same n within a wave)
        ss += __shfl_xor(ss, 16);
        ss += __shfl_xor(ss, 32);
        if (lane < 16) wred[w][lane] = ss;
    }
    __syncthreads();

    // ---- dots via MFMA (waves 0-7: n = w) || rinv (waves 8-9) ----
    if (w < 8) {
        int n = w;
        f32x4 d0 = {0.f, 0.f, 0.f, 0.f};
        const f16* qrow = qkw + (size_t)b * 2048 + (m16 & 7) * 256;
#pragma unroll
        for (int ks = 0; ks < 8; ++ks) {
            f16x8 a0 = *(const f16x8*)a_addr(A, m16, n * 256 + ks * 32 + quad * 8);
            f16x8 bq = *(const f16x8*)(qrow + ks * 32 + quad * 8);
            d0 = __builtin_amdgcn_mfma_f32_16x16x32_f16(a0, bq, d0, 0, 0, 0);
        }
        if (m16 < 8) {   // D: col=m16=e, row=quad*4+r=px
#pragma unroll
            for (int r = 0; r < 4; ++r) dotsP[n][m16][quad * 4 + r] = d0[r];
        }
    } else if (w < 10) {
        int i = t - 512;                  // 0..127 -> (px, n)
        int p = i & 15, n = i >> 4;
        float ss = wred[2 * n][p] + wred[2 * n + 1][p];
        rinvL[p][n] = rsqrtf(ss * (1.f / 256.f) + 1e-6f);
    }
    __syncthreads();

    // ---- fused softmax + blend (in place over A), thread = (px, 4-c window) ----
    // Self-contained in place: thread reads A[px][n*256+cw*4] for all n, writes
    // A[px][e*256+cw*4] for all e — identical address set, no cross-thread hazard.
    {
        int bpx = t & 15;
        int cw = t >> 4;                  // 0..63
        float rinv[8];
#pragma unroll
        for (int n = 0; n < 8; ++n) rinv[n] = rinvL[bpx][n];
        f16x4 cv[8];
#pragma unroll
        for (int n = 0; n < 8; ++n)
            cv[n] = *(const f16x4*)a_addr(A, bpx, n * 256 + cw * 4);
#pragma unroll
        for (int e = 0; e < 8; ++e) {
            float l[8];
#pragma unroll
            for (int n = 0; n < 8; ++n) l[n] = dotsP[n][e][bpx] * rinv[n] * 0.125f;
            float mx = l[0];
#pragma unroll
            for (int n = 1; n < 8; ++n) mx = fmaxf(mx, l[n]);
            float s = 0.f;
#pragma unroll
            for (int n = 0; n < 8; ++n) { l[n] = __expf(l[n] - mx); s += l[n]; }
            float inv = 1.f / s;
            f16x4 r = {};
#pragma unroll
            for (int n = 0; n < 8; ++n) {
                f16 an = (f16)(l[n] * inv * rinv[n]);
#pragma unroll
                for (int j = 0; j < 4; ++j) r[j] += cv[n][j] * an;   // v_pk_fma_f16
            }
            *(f16x4*)a_addr(A, bpx, e * 256 + cw * 4) = r;
        }
    }
    __syncthreads();

    // ---- GEMM: out[16px][256o] = A[16][2048] @ M  (wave w -> o 16-slice) ----
    {
        int o = (w << 4) | m16;
        float bo = b_out[o];              // in flight across the loop
        f32x4 acc = {0.f, 0.f, 0.f, 0.f};
#pragma unroll 4
        for (int ks = 0; ks < 64; ++ks) {
            int k = ks * 32 + quad * 8;
            f16x8 bfr = *(const f16x8*)(mtp + ((size_t)(ks * 4 + quad) * 256 + o) * 8);
            f16x8 af  = *(const f16x8*)a_addr(A, m16, k);
            acc = __builtin_amdgcn_mfma_f32_16x16x32_f16(af, bfr, acc, 0, 0, 0);
        }
        float* drow = out + ((size_t)b * 256 + o) * 1024 + hw0;
        float4 v0 = {acc[0] + bo, acc[1] + bo, acc[2] + bo, acc[3] + bo};
        *(float4*)(drow + quad * 4) = v0;  // D: col=m16=o, row=quad*4+r=px
    }
}

extern "C" void kernel_launch(void* const* d_in, const int* in_sizes, int n_in,
                              void* d_out, int out_size, void* d_ws, size_t ws_size,
                              hipStream_t stream) {
    (void)in_sizes; (void)n_in; (void)out_size; (void)ws_size;
    const int*   q     = (const int*)d_in[0];
    const float* c     = (const float*)d_in[1];
    const float* rms_w = (const float*)d_in[2];
    const float* emb   = (const float*)d_in[3];
    const float* w1    = (const float*)d_in[4];
    const float* b1    = (const float*)d_in[5];
    const float* w2    = (const float*)d_in[6];
    const float* b2    = (const float*)d_in[7];
    const float* w_kv  = (const float*)d_in[8];
    const float* w_out = (const float*)d_in[9];
    const float* b_out = (const float*)d_in[10];
    float* out = (float*)d_out;

    // ws layout: qkw [8b][8e][256c] f16 = 32 KiB at 0; mtp [256kc][256o][8] f16 = 1 MiB
    char* ws = (char*)d_ws;
    f16* qkw = (f16*)ws;                 // [0, 32768)
    f16* mtp = (f16*)(ws + 32768);       // [32768, +1 MiB)

    k_setup<<<320, 256, 0, stream>>>(q, emb, w1, b1, w2, b2, w_kv, w_out, rms_w, qkw, mtp);
    k_attn <<<512, 1024, 0, stream>>>(c, qkw, mtp, b_out, out);
}